// Round 2
// baseline (641.891 us; speedup 1.0000x reference)
//
#include <hip/hip_runtime.h>
#include <hip/hip_bf16.h>

// Problem: b=4, n=2048, dm=1024, heads=16, d=64. SCALE = 1024^-0.5 = 1/32.
// Inputs/outputs are FLOAT32 (per reference). Compute in bf16 MFMA + f32 accum
// (threshold = 2% of absmax accommodates this).
// Pipeline: [1] QKV GEMM (x @ w_qkv^T, f32 in -> bf16 ws) scattered to q/k/v [b,h,n,d]
//           [2] flash attention per (b,h) -> ctx bf16 [b,n,dm] in ws
//           [3] out GEMM (ctx @ w_out^T + b_out) -> d_out f32

typedef __attribute__((ext_vector_type(8))) short short8;   // 8 bf16 = 4 VGPRs (MFMA A/B frag)
typedef __attribute__((ext_vector_type(4))) float float4x;  // MFMA C/D frag (16x16)

#define SCALE 0.03125f
#define QS 8388608      // elements per q/k/v tensor (4*16*2048*64)

static __device__ __forceinline__ short f2bf(float f) {
    union { float f; unsigned u; } x; x.f = f;
    unsigned r = x.u + 0x7fffu + ((x.u >> 16) & 1u);   // round-to-nearest-even
    return (short)(r >> 16);
}
static __device__ __forceinline__ float bf2f(short b) {
    union { unsigned u; float f; } x; x.u = ((unsigned)(unsigned short)b) << 16;
    return x.f;
}

// C[M,N] = A[M,K] @ W[N,K]^T. A_F32: A is f32 (else bf16). W always f32.
// MODE 0: f32 row-major out + bias. MODE 1: bf16 scatter QKV -> out + c*QS, [b,h,n,d].
template<int A_F32, int MODE>
__global__ __launch_bounds__(256) void gemm_bt_kernel(
    const void* __restrict__ Ap, const float* __restrict__ W,
    const float* __restrict__ bias, void* __restrict__ outp,
    int M, int N, int K)
{
    __shared__ __align__(16) short As[64][72];   // +8 pad breaks bank conflicts
    __shared__ __align__(16) short Ws[64][72];

    const int tid  = threadIdx.x;
    const int wave = tid >> 6;
    const int lane = tid & 63;
    const int row16 = lane & 15;
    const int quad  = lane >> 4;
    const int m0 = blockIdx.x * 64;
    const int n0 = blockIdx.y * 64;

    float4x acc[4];
    for (int jt = 0; jt < 4; jt++) acc[jt] = (float4x){0.f, 0.f, 0.f, 0.f};

    for (int kb = 0; kb < K; kb += 64) {
        __syncthreads();
        // ---- stage W (f32 -> bf16): 64x64 floats = 1024 float4 chunks, 4/thread
        for (int r = 0; r < 4; r++) {
            int i = tid + r * 256;
            int row = i >> 4, cb = i & 15;
            float4 wv = *(const float4*)(W + (size_t)(n0 + row) * K + kb + cb * 4);
            short t[4] = {f2bf(wv.x), f2bf(wv.y), f2bf(wv.z), f2bf(wv.w)};
            *(uint2*)&Ws[row][cb * 4] = *(uint2*)t;
        }
        // ---- stage A
        if (A_F32) {
            const float* A = (const float*)Ap;
            for (int r = 0; r < 4; r++) {
                int i = tid + r * 256;
                int row = i >> 4, cb = i & 15;
                float4 av = *(const float4*)(A + (size_t)(m0 + row) * K + kb + cb * 4);
                short t[4] = {f2bf(av.x), f2bf(av.y), f2bf(av.z), f2bf(av.w)};
                *(uint2*)&As[row][cb * 4] = *(uint2*)t;
            }
        } else {
            const short* A = (const short*)Ap;
            for (int r = 0; r < 2; r++) {
                int i = tid + r * 256;
                int row = i >> 3, cb = i & 7;
                *(uint4*)&As[row][cb * 8] = *(const uint4*)(A + (size_t)(m0 + row) * K + kb + cb * 8);
            }
        }
        __syncthreads();
        // A-frag: A[m=lane&15][k=quad*8+j]; W rows act as B^T so same frag pattern.
        short8 a0 = *(const short8*)&As[wave * 16 + row16][quad * 8];
        short8 a1 = *(const short8*)&As[wave * 16 + row16][32 + quad * 8];
        for (int jt = 0; jt < 4; jt++) {
            short8 b0 = *(const short8*)&Ws[jt * 16 + row16][quad * 8];
            short8 b1 = *(const short8*)&Ws[jt * 16 + row16][32 + quad * 8];
            acc[jt] = __builtin_amdgcn_mfma_f32_16x16x32_bf16(a0, b0, acc[jt], 0, 0, 0);
            acc[jt] = __builtin_amdgcn_mfma_f32_16x16x32_bf16(a1, b1, acc[jt], 0, 0, 0);
        }
    }
    // epilogue: C/D layout row=quad*4+r, col=lane&15
    for (int jt = 0; jt < 4; jt++) {
        for (int r = 0; r < 4; r++) {
            int mm = m0 + wave * 16 + quad * 4 + r;
            int nn = n0 + jt * 16 + row16;
            float v = acc[jt][r];
            if (MODE == 0) {
                ((float*)outp)[(size_t)mm * N + nn] = v + bias[nn];
            } else {
                int c   = nn >> 10;        // 0=q 1=k 2=v
                int rem = nn & 1023;
                int hh  = rem >> 6;
                int dd  = rem & 63;
                int bb  = mm >> 11;
                int nsq = mm & 2047;
                ((short*)outp)[(size_t)c * QS + (((size_t)(bb * 16 + hh) * 2048 + nsq) * 64 + dd)] = f2bf(v);
            }
        }
    }
}

// Flash attention: one block = one (b,h) x one 64-row Q tile. 4 waves, each owns
// a 16-row strip. Online softmax; P round-trips through LDS (C-layout -> A-layout).
__global__ __launch_bounds__(256) void flash_kernel(
    const short* __restrict__ Q, const short* __restrict__ Km,
    const short* __restrict__ V, short* __restrict__ ctx)
{
    __shared__ __align__(16) short Qs[64][72];
    __shared__ __align__(16) short Ks[64][72];
    __shared__ __align__(16) short VTs[64][72];      // V transposed: VT[d][j]
    __shared__ __align__(16) short Ps[4][16][72];    // per-wave P tile

    const int qt = blockIdx.x;       // 0..31
    const int bh = blockIdx.y;       // 0..63
    const int tid  = threadIdx.x;
    const int wave = tid >> 6;
    const int lane = tid & 63;
    const int row16 = lane & 15;
    const int quad  = lane >> 4;
    const size_t base = (size_t)bh * 2048 * 64;

    for (int r = 0; r < 2; r++) {
        int i = tid + r * 256; int row = i >> 3, cb = i & 7;
        *(uint4*)&Qs[row][cb * 8] = *(const uint4*)(Q + base + (size_t)(qt * 64 + row) * 64 + cb * 8);
    }
    __syncthreads();
    short8 q0 = *(const short8*)&Qs[wave * 16 + row16][quad * 8];
    short8 q1 = *(const short8*)&Qs[wave * 16 + row16][32 + quad * 8];

    float m_i[4], l_i[4];
    float4x accO[4];
    for (int r = 0; r < 4; r++) { m_i[r] = -1e30f; l_i[r] = 0.f; }
    for (int dt = 0; dt < 4; dt++) accO[dt] = (float4x){0.f, 0.f, 0.f, 0.f};

    for (int kt = 0; kt < 32; kt++) {
        __syncthreads();   // protect prev-iter K/VT/P reads
        for (int r = 0; r < 2; r++) {
            int i = tid + r * 256; int row = i >> 3, cb = i & 7;
            *(uint4*)&Ks[row][cb * 8] = *(const uint4*)(Km + base + (size_t)(kt * 64 + row) * 64 + cb * 8);
            uint4 vv = *(const uint4*)(V + base + (size_t)(kt * 64 + row) * 64 + cb * 8);
            const short* vs = (const short*)&vv;
            for (int e = 0; e < 8; e++) VTs[cb * 8 + e][row] = vs[e];   // transpose on store
        }
        __syncthreads();

        // S = Q K^T * SCALE  (K rows are the S columns -> B^T pattern, same frag load)
        float sv[4][4];
        for (int jt = 0; jt < 4; jt++) {
            short8 b0 = *(const short8*)&Ks[jt * 16 + row16][quad * 8];
            short8 b1 = *(const short8*)&Ks[jt * 16 + row16][32 + quad * 8];
            float4x s = (float4x){0.f, 0.f, 0.f, 0.f};
            s = __builtin_amdgcn_mfma_f32_16x16x32_bf16(q0, b0, s, 0, 0, 0);
            s = __builtin_amdgcn_mfma_f32_16x16x32_bf16(q1, b1, s, 0, 0, 0);
            for (int r = 0; r < 4; r++) sv[jt][r] = s[r] * SCALE;
        }
        // online softmax (rows = quad*4+r; 16 lanes of a quad share a row's 16 cols)
        for (int r = 0; r < 4; r++) {
            float v = fmaxf(fmaxf(sv[0][r], sv[1][r]), fmaxf(sv[2][r], sv[3][r]));
            for (int off = 1; off < 16; off <<= 1) v = fmaxf(v, __shfl_xor(v, off, 64));
            float mnew = fmaxf(m_i[r], v);
            float alpha = __expf(m_i[r] - mnew);
            float rsum = 0.f;
            for (int jt = 0; jt < 4; jt++) {
                float p = __expf(sv[jt][r] - mnew);
                sv[jt][r] = p; rsum += p;
            }
            for (int off = 1; off < 16; off <<= 1) rsum += __shfl_xor(rsum, off, 64);
            l_i[r] = l_i[r] * alpha + rsum;
            m_i[r] = mnew;
            for (int dt = 0; dt < 4; dt++) accO[dt][r] *= alpha;
        }
        // P: C-layout -> LDS -> A-layout
        for (int jt = 0; jt < 4; jt++)
            for (int r = 0; r < 4; r++)
                Ps[wave][quad * 4 + r][jt * 16 + row16] = f2bf(sv[jt][r]);
        __syncthreads();
        short8 p0 = *(const short8*)&Ps[wave][row16][quad * 8];
        short8 p1 = *(const short8*)&Ps[wave][row16][32 + quad * 8];
        for (int dt = 0; dt < 4; dt++) {
            short8 v0 = *(const short8*)&VTs[dt * 16 + row16][quad * 8];
            short8 v1 = *(const short8*)&VTs[dt * 16 + row16][32 + quad * 8];
            accO[dt] = __builtin_amdgcn_mfma_f32_16x16x32_bf16(p0, v0, accO[dt], 0, 0, 0);
            accO[dt] = __builtin_amdgcn_mfma_f32_16x16x32_bf16(p1, v1, accO[dt], 0, 0, 0);
        }
    }
    // epilogue: ctx[b, n, h*64+d] = O / l   (bf16 ws)
    const int bb = bh >> 4, hh = bh & 15;
    for (int dt = 0; dt < 4; dt++) {
        for (int r = 0; r < 4; r++) {
            int nn = qt * 64 + wave * 16 + quad * 4 + r;
            float o = accO[dt][r] / l_i[r];
            ctx[(size_t)(bb * 2048 + nn) * 1024 + hh * 64 + dt * 16 + row16] = f2bf(o);
        }
    }
}

extern "C" void kernel_launch(void* const* d_in, const int* in_sizes, int n_in,
                              void* d_out, int out_size, void* d_ws, size_t ws_size,
                              hipStream_t stream) {
    const float* x     = (const float*)d_in[0];   // [4,2048,1024] f32
    const float* w_qkv = (const float*)d_in[1];   // [3072,1024]  f32
    const float* w_out = (const float*)d_in[2];   // [1024,1024]  f32
    const float* b_out = (const float*)d_in[3];   // [1024]       f32
    float* out = (float*)d_out;                   // [4,2048,1024] f32
    short* ws  = (short*)d_ws;
    short* qkv_ws = ws;                           // q,k,v each QS bf16, [b,h,n,d]
    short* ctx_ws = ws + (size_t)3 * QS;          // [b,n,dm] bf16

    dim3 blk(256);
    // [1] QKV projection (f32 A/W), scatter bf16 epilogue
    gemm_bt_kernel<1, 1><<<dim3(128, 48), blk, 0, stream>>>(x, w_qkv, nullptr, qkv_ws,
                                                            8192, 3072, 1024);
    // [2] flash attention (bf16 ws)
    flash_kernel<<<dim3(32, 64), blk, 0, stream>>>(qkv_ws, qkv_ws + QS, qkv_ws + 2 * (size_t)QS,
                                                   ctx_ws);
    // [3] output projection + bias -> f32 out
    gemm_bt_kernel<0, 0><<<dim3(128, 16), blk, 0, stream>>>(ctx_ws, w_out, b_out, out,
                                                            8192, 1024, 1024);
}

// Round 3
// 500.022 us; speedup vs baseline: 1.2837x; 1.2837x over previous
//
#include <hip/hip_runtime.h>
#include <hip/hip_bf16.h>

// Problem: b=4, n=2048, dm=1024, heads=16, d=64. SCALE = 1024^-0.5 = 1/32.
// Inputs/outputs FLOAT32; compute in bf16 MFMA + f32 accum (2%-absmax threshold).
// Pipeline: [1] QKV GEMM (f32 in -> bf16 ws): q,k -> [b,h,n,d]; v -> TRANSPOSED [b,h,d,n]
//           [2] flash attention (S^T orientation, vectorized P round-trip) -> ctx bf16
//           [3] out GEMM (ctx @ w_out^T + b_out) -> d_out f32

typedef __attribute__((ext_vector_type(8))) short short8;   // 8 bf16 = 4 VGPRs (MFMA A/B frag)
typedef __attribute__((ext_vector_type(4))) float float4x;  // MFMA C/D frag (16x16)

#define SCALE 0.03125f
#define QS 8388608      // elements per q/k/v tensor (4*16*2048*64)

static __device__ __forceinline__ short f2bf(float f) {
    union { float f; unsigned u; } x; x.f = f;
    unsigned r = x.u + 0x7fffu + ((x.u >> 16) & 1u);   // round-to-nearest-even
    return (short)(r >> 16);
}
static __device__ __forceinline__ unsigned pack2(float a, float b) {
    return (unsigned)(unsigned short)f2bf(a) | ((unsigned)(unsigned short)f2bf(b) << 16);
}

// C[M,N] = A[M,K] @ W[N,K]^T. A_F32: A is f32 (else bf16). W always f32.
// MODE 0: f32 row-major out + bias. MODE 1: bf16 scatter QKV; q,k [b,h,n,d]; v [b,h,d,n].
template<int A_F32, int MODE>
__global__ __launch_bounds__(256) void gemm_bt_kernel(
    const void* __restrict__ Ap, const float* __restrict__ W,
    const float* __restrict__ bias, void* __restrict__ outp,
    int M, int N, int K)
{
    __shared__ __align__(16) short As[64][72];   // +8 pad breaks bank conflicts
    __shared__ __align__(16) short Ws[64][72];

    const int tid  = threadIdx.x;
    const int wave = tid >> 6;
    const int lane = tid & 63;
    const int row16 = lane & 15;
    const int quad  = lane >> 4;
    const int m0 = blockIdx.x * 64;
    const int n0 = blockIdx.y * 64;

    float4x acc[4];
    for (int jt = 0; jt < 4; jt++) acc[jt] = (float4x){0.f, 0.f, 0.f, 0.f};

    for (int kb = 0; kb < K; kb += 64) {
        __syncthreads();
        // ---- stage W (f32 -> bf16): 64x64 floats = 1024 float4 chunks, 4/thread
        for (int r = 0; r < 4; r++) {
            int i = tid + r * 256;
            int row = i >> 4, cb = i & 15;
            float4 wv = *(const float4*)(W + (size_t)(n0 + row) * K + kb + cb * 4);
            unsigned t[2] = {pack2(wv.x, wv.y), pack2(wv.z, wv.w)};
            *(uint2*)&Ws[row][cb * 4] = *(uint2*)t;
        }
        // ---- stage A
        if (A_F32) {
            const float* A = (const float*)Ap;
            for (int r = 0; r < 4; r++) {
                int i = tid + r * 256;
                int row = i >> 4, cb = i & 15;
                float4 av = *(const float4*)(A + (size_t)(m0 + row) * K + kb + cb * 4);
                unsigned t[2] = {pack2(av.x, av.y), pack2(av.z, av.w)};
                *(uint2*)&As[row][cb * 4] = *(uint2*)t;
            }
        } else {
            const short* A = (const short*)Ap;
            for (int r = 0; r < 2; r++) {
                int i = tid + r * 256;
                int row = i >> 3, cb = i & 7;
                *(uint4*)&As[row][cb * 8] = *(const uint4*)(A + (size_t)(m0 + row) * K + kb + cb * 8);
            }
        }
        __syncthreads();
        // A-frag: A[m=lane&15][k=quad*8+j]; W rows act as B^T so same frag pattern.
        short8 a0 = *(const short8*)&As[wave * 16 + row16][quad * 8];
        short8 a1 = *(const short8*)&As[wave * 16 + row16][32 + quad * 8];
        for (int jt = 0; jt < 4; jt++) {
            short8 b0 = *(const short8*)&Ws[jt * 16 + row16][quad * 8];
            short8 b1 = *(const short8*)&Ws[jt * 16 + row16][32 + quad * 8];
            acc[jt] = __builtin_amdgcn_mfma_f32_16x16x32_bf16(a0, b0, acc[jt], 0, 0, 0);
            acc[jt] = __builtin_amdgcn_mfma_f32_16x16x32_bf16(a1, b1, acc[jt], 0, 0, 0);
        }
    }
    // epilogue: C/D layout row=quad*4+r, col=lane&15
    for (int jt = 0; jt < 4; jt++) {
        for (int r = 0; r < 4; r++) {
            int mm = m0 + wave * 16 + quad * 4 + r;
            int nn = n0 + jt * 16 + row16;
            float v = acc[jt][r];
            if (MODE == 0) {
                ((float*)outp)[(size_t)mm * N + nn] = v + bias[nn];
            } else {
                int c   = nn >> 10;        // 0=q 1=k 2=v
                int rem = nn & 1023;
                int hh  = rem >> 6;
                int dd  = rem & 63;
                int bb  = mm >> 11;
                int nsq = mm & 2047;
                size_t off;
                if (c == 2)  // V transposed: [b,h,d,n]
                    off = 2 * (size_t)QS + (((size_t)(bb * 16 + hh) * 64 + dd) * 2048 + nsq);
                else
                    off = (size_t)c * QS + (((size_t)(bb * 16 + hh) * 2048 + nsq) * 64 + dd);
                ((short*)outp)[off] = f2bf(v);
            }
        }
    }
}

// Flash attention, S^T orientation. One block = one (b,h) x one 64-row Q tile;
// 4 waves, each owns a 16-row Q strip (row i = lane&15; the 4 quads split the j/d dims).
// S^T = K·Q^T  (C-layout: lane holds S[i=lane&15][j=jt*16+quad*4+r])
// O^T = V^T·P^T (VT staged directly; P^T B-frag via vectorized wave-private LDS round trip)
__global__ __launch_bounds__(256) void flash_kernel(
    const short* __restrict__ Q, const short* __restrict__ Km,
    const short* __restrict__ VT, short* __restrict__ ctx)
{
    __shared__ __align__(16) short Qs[64][72];
    __shared__ __align__(16) short Ks[64][72];
    __shared__ __align__(16) short VTs[64][72];     // [d][j] direct copy
    __shared__ __align__(16) short Ps[4][16][80];   // per-wave P[i][j], stride 80 vs conflicts

    const int qt = blockIdx.x;       // 0..31
    const int bh = blockIdx.y;       // 0..63
    const int tid  = threadIdx.x;
    const int wave = tid >> 6;
    const int lane = tid & 63;
    const int row16 = lane & 15;
    const int quad  = lane >> 4;
    const size_t basekq = (size_t)bh * 2048 * 64;   // Q/K: [n][d]
    const size_t basev  = (size_t)bh * 64 * 2048;   // VT:  [d][n]

    for (int r = 0; r < 2; r++) {
        int i = tid + r * 256; int row = i >> 3, cb = i & 7;
        *(uint4*)&Qs[row][cb * 8] = *(const uint4*)(Q + basekq + (size_t)(qt * 64 + row) * 64 + cb * 8);
    }
    __syncthreads();
    // Q as B-operand of S^T=K·Q^T: lane n=i=row16, k=d=quad*8+e
    short8 q0 = *(const short8*)&Qs[wave * 16 + row16][quad * 8];
    short8 q1 = *(const short8*)&Qs[wave * 16 + row16][32 + quad * 8];

    float m_i = -1e30f, l_i = 0.f;
    float4x accO[4];
    for (int dt = 0; dt < 4; dt++) accO[dt] = (float4x){0.f, 0.f, 0.f, 0.f};

    for (int kt = 0; kt < 32; kt++) {
        __syncthreads();   // protect prev-iter Ks/VTs reads
        for (int r = 0; r < 2; r++) {
            int i = tid + r * 256; int row = i >> 3, cb = i & 7;
            *(uint4*)&Ks[row][cb * 8]  = *(const uint4*)(Km + basekq + (size_t)(kt * 64 + row) * 64 + cb * 8);
            *(uint4*)&VTs[row][cb * 8] = *(const uint4*)(VT + basev + (size_t)row * 2048 + kt * 64 + cb * 8);
        }
        __syncthreads();

        // S^T = K·Q^T, scaled: sv[jt][r] = S[i=row16][j=jt*16+quad*4+r]*SCALE
        float sv[4][4];
        for (int jt = 0; jt < 4; jt++) {
            short8 k0 = *(const short8*)&Ks[jt * 16 + row16][quad * 8];
            short8 k1 = *(const short8*)&Ks[jt * 16 + row16][32 + quad * 8];
            float4x s = (float4x){0.f, 0.f, 0.f, 0.f};
            s = __builtin_amdgcn_mfma_f32_16x16x32_bf16(k0, q0, s, 0, 0, 0);
            s = __builtin_amdgcn_mfma_f32_16x16x32_bf16(k1, q1, s, 0, 0, 0);
            for (int r = 0; r < 4; r++) sv[jt][r] = s[r] * SCALE;
        }
        // online softmax: each lane owns row i=row16's 16 j-values; combine quads via xor16/32
        float vmax = sv[0][0];
        for (int jt = 0; jt < 4; jt++)
            for (int r = 0; r < 4; r++) vmax = fmaxf(vmax, sv[jt][r]);
        vmax = fmaxf(vmax, __shfl_xor(vmax, 16, 64));
        vmax = fmaxf(vmax, __shfl_xor(vmax, 32, 64));
        float mnew = fmaxf(m_i, vmax);
        float alpha = __expf(m_i - mnew);
        float rsum = 0.f;
        for (int jt = 0; jt < 4; jt++) {
            float e0 = __expf(sv[jt][0] - mnew);
            float e1 = __expf(sv[jt][1] - mnew);
            float e2 = __expf(sv[jt][2] - mnew);
            float e3 = __expf(sv[jt][3] - mnew);
            rsum += (e0 + e1) + (e2 + e3);
            uint2 w; w.x = pack2(e0, e1); w.y = pack2(e2, e3);
            *(uint2*)&Ps[wave][row16][jt * 16 + quad * 4] = w;   // ds_write_b64, j-contiguous
        }
        rsum += __shfl_xor(rsum, 16, 64);
        rsum += __shfl_xor(rsum, 32, 64);
        l_i = l_i * alpha + rsum;
        m_i = mnew;
        for (int dt = 0; dt < 4; dt++)
            for (int r = 0; r < 4; r++) accO[dt][r] *= alpha;

        __builtin_amdgcn_wave_barrier();   // wave-private Ps: no s_barrier needed (DS in-order)
        // P^T B-frag: lane n=i=row16, k=j=quad*8+e
        short8 p0 = *(const short8*)&Ps[wave][row16][quad * 8];
        short8 p1 = *(const short8*)&Ps[wave][row16][32 + quad * 8];
        for (int dt = 0; dt < 4; dt++) {
            short8 v0 = *(const short8*)&VTs[dt * 16 + row16][quad * 8];
            short8 v1 = *(const short8*)&VTs[dt * 16 + row16][32 + quad * 8];
            accO[dt] = __builtin_amdgcn_mfma_f32_16x16x32_bf16(v0, p0, accO[dt], 0, 0, 0);
            accO[dt] = __builtin_amdgcn_mfma_f32_16x16x32_bf16(v1, p1, accO[dt], 0, 0, 0);
        }
    }
    // epilogue: lane holds O[i=row16][d=dt*16+quad*4+r]; 4 bf16 contiguous per dt
    const int bb = bh >> 4, hh = bh & 15;
    const float inv = 1.f / l_i;
    const int nrow = qt * 64 + wave * 16 + row16;
    for (int dt = 0; dt < 4; dt++) {
        uint2 w;
        w.x = pack2(accO[dt][0] * inv, accO[dt][1] * inv);
        w.y = pack2(accO[dt][2] * inv, accO[dt][3] * inv);
        *(uint2*)(ctx + (size_t)(bb * 2048 + nrow) * 1024 + hh * 64 + dt * 16 + quad * 4) = w;
    }
}

extern "C" void kernel_launch(void* const* d_in, const int* in_sizes, int n_in,
                              void* d_out, int out_size, void* d_ws, size_t ws_size,
                              hipStream_t stream) {
    const float* x     = (const float*)d_in[0];   // [4,2048,1024] f32
    const float* w_qkv = (const float*)d_in[1];   // [3072,1024]  f32
    const float* w_out = (const float*)d_in[2];   // [1024,1024]  f32
    const float* b_out = (const float*)d_in[3];   // [1024]       f32
    float* out = (float*)d_out;                   // [4,2048,1024] f32
    short* ws  = (short*)d_ws;
    short* qkv_ws = ws;                           // q,k [b,h,n,d]; v [b,h,d,n]; bf16
    short* ctx_ws = ws + (size_t)3 * QS;          // [b,n,dm] bf16

    dim3 blk(256);
    // [1] QKV projection (f32 A/W), scatter bf16 epilogue (V transposed)
    gemm_bt_kernel<1, 1><<<dim3(128, 48), blk, 0, stream>>>(x, w_qkv, nullptr, qkv_ws,
                                                            8192, 3072, 1024);
    // [2] flash attention (bf16 ws)
    flash_kernel<<<dim3(32, 64), blk, 0, stream>>>(qkv_ws, qkv_ws + QS, qkv_ws + 2 * (size_t)QS,
                                                   ctx_ws);
    // [3] output projection + bias -> f32 out
    gemm_bt_kernel<0, 0><<<dim3(128, 16), blk, 0, stream>>>(ctx_ws, w_out, b_out, out,
                                                            8192, 1024, 1024);
}

// Round 4
// 377.667 us; speedup vs baseline: 1.6996x; 1.3240x over previous
//
#include <hip/hip_runtime.h>
#include <hip/hip_bf16.h>

// Problem: b=4, n=2048, dm=1024, heads=16, d=64. SCALE = 1024^-0.5 = 1/32.
// Inputs/outputs FLOAT32; compute in bf16 MFMA + f32 accum (2%-absmax threshold).
// Pipeline: [0] cast f32->bf16 (x, w_qkv, w_out) into ws
//           [1] QKV GEMM (m97-style 128x128, global_load_lds): q,k [b,h,n,d]; v [b,h,d,n]
//           [2] flash attention (S^T orientation) -> ctx bf16 (aliases x_bf16 slot)
//           [3] out GEMM 128x128 + bias -> d_out f32

typedef __attribute__((ext_vector_type(8))) short short8;   // 8 bf16 (4 VGPRs) MFMA A/B frag
typedef __attribute__((ext_vector_type(4))) float float4x;  // MFMA C/D frag (16x16)

#define SCALE 0.03125f
#define QS 8388608      // elements per q/k/v tensor (4*16*2048*64) == elements of x

static __device__ __forceinline__ short f2bf(float f) {
    union { float f; unsigned u; } x; x.f = f;
    unsigned r = x.u + 0x7fffu + ((x.u >> 16) & 1u);   // round-to-nearest-even
    return (short)(r >> 16);
}
static __device__ __forceinline__ unsigned pack2(float a, float b) {
    return (unsigned)(unsigned short)f2bf(a) | ((unsigned)(unsigned short)f2bf(b) << 16);
}
static __device__ __forceinline__ void async16(const void* g, void* l) {
    __builtin_amdgcn_global_load_lds(
        (const __attribute__((address_space(1))) void*)g,
        (__attribute__((address_space(3))) void*)l, 16, 0, 0);
}

// [0] f32 -> bf16 cast: x (2097152 float4), w_qkv (786432), w_out (262144). 1 float4/thread.
__global__ __launch_bounds__(256) void cast_kernel(
    const float* __restrict__ x, const float* __restrict__ wq, const float* __restrict__ wo,
    short* __restrict__ xo, short* __restrict__ wqo, short* __restrict__ woo)
{
    int i = blockIdx.x * 256 + threadIdx.x;      // 0 .. 3145727
    const float* src; short* dst; int off;
    if (i < 2097152)      { src = x;  dst = xo;  off = i; }
    else if (i < 2883584) { src = wq; dst = wqo; off = i - 2097152; }
    else                  { src = wo; dst = woo; off = i - 2883584; }
    float4 v = *(const float4*)(src + (size_t)off * 4);
    unsigned t[2] = {pack2(v.x, v.y), pack2(v.z, v.w)};
    *(uint2*)(dst + (size_t)off * 4) = *(uint2*)t;
}

// C[M,N] = A[M,K] @ W[N,K]^T, bf16 in. 128x128 tile, BK=64, global_load_lds staging.
// 4 waves 2x2; each wave 64x64 = 4x4 frags of 16x16x32.
// MODE 0: f32 row-major out + bias. MODE 1: bf16 scatter QKV; q,k [b,h,n,d]; v [b,h,d,n].
template<int MODE>
__global__ __launch_bounds__(256) void gemm_bt_kernel(
    const short* __restrict__ A, const short* __restrict__ W,
    const float* __restrict__ bias, void* __restrict__ outp,
    int M, int N, int K)
{
    // NOTE: no padding — global_load_lds requires LDS contiguous in lane order.
    __shared__ short As[128 * 64];
    __shared__ short Ws[128 * 64];

    const int tid  = threadIdx.x;
    const int lane = tid & 63;
    const int wave = tid >> 6;
    const int row16 = lane & 15;
    const int quad  = lane >> 4;
    const int wm = wave >> 1, wn = wave & 1;
    const int m0 = blockIdx.x * 128;
    const int n0 = blockIdx.y * 128;

    float4x acc[4][4] = {};

    for (int kb = 0; kb < K; kb += 64) {
        __syncthreads();   // protect prev-iter LDS reads
        // stage A,W tiles: 128 rows x 64 cols bf16 = 16 KB each; 16B/lane/insn, 4 insn/matrix
        for (int r = 0; r < 4; r++) {
            int i = r * 256 + tid;          // 0..1023 chunk index
            int row = i >> 3, ch = i & 7;
            async16(A + (size_t)(m0 + row) * K + kb + ch * 8, &As[i * 8]);
        }
        for (int r = 0; r < 4; r++) {
            int i = r * 256 + tid;
            int row = i >> 3, ch = i & 7;
            async16(W + (size_t)(n0 + row) * K + kb + ch * 8, &Ws[i * 8]);
        }
        __syncthreads();   // drains vmcnt (compiler inserts waitcnt before barrier)

        short8 af[4][2], bfr[4][2];
        for (int mt = 0; mt < 4; mt++)
            for (int h = 0; h < 2; h++)
                af[mt][h] = *(const short8*)&As[(wm * 64 + mt * 16 + row16) * 64 + h * 32 + quad * 8];
        for (int nt = 0; nt < 4; nt++)
            for (int h = 0; h < 2; h++)
                bfr[nt][h] = *(const short8*)&Ws[(wn * 64 + nt * 16 + row16) * 64 + h * 32 + quad * 8];
        for (int mt = 0; mt < 4; mt++)
            for (int nt = 0; nt < 4; nt++) {
                acc[mt][nt] = __builtin_amdgcn_mfma_f32_16x16x32_bf16(af[mt][0], bfr[nt][0], acc[mt][nt], 0, 0, 0);
                acc[mt][nt] = __builtin_amdgcn_mfma_f32_16x16x32_bf16(af[mt][1], bfr[nt][1], acc[mt][nt], 0, 0, 0);
            }
    }
    // epilogue: C/D layout row=quad*4+r, col=row16
    for (int mt = 0; mt < 4; mt++) {
        for (int nt = 0; nt < 4; nt++) {
            for (int r = 0; r < 4; r++) {
                int mm = m0 + wm * 64 + mt * 16 + quad * 4 + r;
                int nn = n0 + wn * 64 + nt * 16 + row16;
                float v = acc[mt][nt][r];
                if (MODE == 0) {
                    ((float*)outp)[(size_t)mm * N + nn] = v + bias[nn];
                } else {
                    int c   = nn >> 10;        // 0=q 1=k 2=v
                    int rem = nn & 1023;
                    int hh  = rem >> 6;
                    int dd  = rem & 63;
                    int bb  = mm >> 11;
                    int nsq = mm & 2047;
                    size_t off;
                    if (c == 2)  // V transposed: [b,h,d,n]
                        off = 2 * (size_t)QS + (((size_t)(bb * 16 + hh) * 64 + dd) * 2048 + nsq);
                    else
                        off = (size_t)c * QS + (((size_t)(bb * 16 + hh) * 2048 + nsq) * 64 + dd);
                    ((short*)outp)[off] = f2bf(v);
                }
            }
        }
    }
}

// Flash attention, S^T orientation (unchanged from round 3 — passes, ~175 us).
__global__ __launch_bounds__(256) void flash_kernel(
    const short* __restrict__ Q, const short* __restrict__ Km,
    const short* __restrict__ VT, short* __restrict__ ctx)
{
    __shared__ __align__(16) short Qs[64][72];
    __shared__ __align__(16) short Ks[64][72];
    __shared__ __align__(16) short VTs[64][72];     // [d][j] direct copy
    __shared__ __align__(16) short Ps[4][16][80];   // per-wave P[i][j]

    const int qt = blockIdx.x;       // 0..31
    const int bh = blockIdx.y;       // 0..63
    const int tid  = threadIdx.x;
    const int wave = tid >> 6;
    const int lane = tid & 63;
    const int row16 = lane & 15;
    const int quad  = lane >> 4;
    const size_t basekq = (size_t)bh * 2048 * 64;   // Q/K: [n][d]
    const size_t basev  = (size_t)bh * 64 * 2048;   // VT:  [d][n]

    for (int r = 0; r < 2; r++) {
        int i = tid + r * 256; int row = i >> 3, cb = i & 7;
        *(uint4*)&Qs[row][cb * 8] = *(const uint4*)(Q + basekq + (size_t)(qt * 64 + row) * 64 + cb * 8);
    }
    __syncthreads();
    short8 q0 = *(const short8*)&Qs[wave * 16 + row16][quad * 8];
    short8 q1 = *(const short8*)&Qs[wave * 16 + row16][32 + quad * 8];

    float m_i = -1e30f, l_i = 0.f;
    float4x accO[4];
    for (int dt = 0; dt < 4; dt++) accO[dt] = (float4x){0.f, 0.f, 0.f, 0.f};

    for (int kt = 0; kt < 32; kt++) {
        __syncthreads();
        for (int r = 0; r < 2; r++) {
            int i = tid + r * 256; int row = i >> 3, cb = i & 7;
            *(uint4*)&Ks[row][cb * 8]  = *(const uint4*)(Km + basekq + (size_t)(kt * 64 + row) * 64 + cb * 8);
            *(uint4*)&VTs[row][cb * 8] = *(const uint4*)(VT + basev + (size_t)row * 2048 + kt * 64 + cb * 8);
        }
        __syncthreads();

        float sv[4][4];
        for (int jt = 0; jt < 4; jt++) {
            short8 k0 = *(const short8*)&Ks[jt * 16 + row16][quad * 8];
            short8 k1 = *(const short8*)&Ks[jt * 16 + row16][32 + quad * 8];
            float4x s = (float4x){0.f, 0.f, 0.f, 0.f};
            s = __builtin_amdgcn_mfma_f32_16x16x32_bf16(k0, q0, s, 0, 0, 0);
            s = __builtin_amdgcn_mfma_f32_16x16x32_bf16(k1, q1, s, 0, 0, 0);
            for (int r = 0; r < 4; r++) sv[jt][r] = s[r] * SCALE;
        }
        float vmax = sv[0][0];
        for (int jt = 0; jt < 4; jt++)
            for (int r = 0; r < 4; r++) vmax = fmaxf(vmax, sv[jt][r]);
        vmax = fmaxf(vmax, __shfl_xor(vmax, 16, 64));
        vmax = fmaxf(vmax, __shfl_xor(vmax, 32, 64));
        float mnew = fmaxf(m_i, vmax);
        float alpha = __expf(m_i - mnew);
        float rsum = 0.f;
        for (int jt = 0; jt < 4; jt++) {
            float e0 = __expf(sv[jt][0] - mnew);
            float e1 = __expf(sv[jt][1] - mnew);
            float e2 = __expf(sv[jt][2] - mnew);
            float e3 = __expf(sv[jt][3] - mnew);
            rsum += (e0 + e1) + (e2 + e3);
            uint2 w; w.x = pack2(e0, e1); w.y = pack2(e2, e3);
            *(uint2*)&Ps[wave][row16][jt * 16 + quad * 4] = w;
        }
        rsum += __shfl_xor(rsum, 16, 64);
        rsum += __shfl_xor(rsum, 32, 64);
        l_i = l_i * alpha + rsum;
        m_i = mnew;
        for (int dt = 0; dt < 4; dt++)
            for (int r = 0; r < 4; r++) accO[dt][r] *= alpha;

        __builtin_amdgcn_wave_barrier();   // wave-private Ps
        short8 p0 = *(const short8*)&Ps[wave][row16][quad * 8];
        short8 p1 = *(const short8*)&Ps[wave][row16][32 + quad * 8];
        for (int dt = 0; dt < 4; dt++) {
            short8 v0 = *(const short8*)&VTs[dt * 16 + row16][quad * 8];
            short8 v1 = *(const short8*)&VTs[dt * 16 + row16][32 + quad * 8];
            accO[dt] = __builtin_amdgcn_mfma_f32_16x16x32_bf16(v0, p0, accO[dt], 0, 0, 0);
            accO[dt] = __builtin_amdgcn_mfma_f32_16x16x32_bf16(v1, p1, accO[dt], 0, 0, 0);
        }
    }
    const int bb = bh >> 4, hh = bh & 15;
    const float inv = 1.f / l_i;
    const int nrow = qt * 64 + wave * 16 + row16;
    for (int dt = 0; dt < 4; dt++) {
        uint2 w;
        w.x = pack2(accO[dt][0] * inv, accO[dt][1] * inv);
        w.y = pack2(accO[dt][2] * inv, accO[dt][3] * inv);
        *(uint2*)(ctx + (size_t)(bb * 2048 + nrow) * 1024 + hh * 64 + dt * 16 + quad * 4) = w;
    }
}

extern "C" void kernel_launch(void* const* d_in, const int* in_sizes, int n_in,
                              void* d_out, int out_size, void* d_ws, size_t ws_size,
                              hipStream_t stream) {
    const float* x     = (const float*)d_in[0];   // [4,2048,1024] f32
    const float* w_qkv = (const float*)d_in[1];   // [3072,1024]  f32
    const float* w_out = (const float*)d_in[2];   // [1024,1024]  f32
    const float* b_out = (const float*)d_in[3];   // [1024]       f32
    float* out = (float*)d_out;                   // [4,2048,1024] f32
    short* ws  = (short*)d_ws;

    short* qkv_ws  = ws;                                   // 3*QS: q,k [b,h,n,d]; v [b,h,d,n]
    short* xbf     = ws + (size_t)3 * QS;                  // QS   (aliased with ctx after GEMM1)
    short* ctx_ws  = xbf;                                  // [b,n,dm] bf16
    short* wqkv_bf = ws + (size_t)4 * QS;                  // 3145728
    short* wout_bf = wqkv_bf + 3145728;                    // 1048576
    // total ws use: 4*QS + 4194304 elems = 75.5 MB

    dim3 blk(256);
    // [0] cast inputs to bf16
    cast_kernel<<<12288, blk, 0, stream>>>(x, w_qkv, w_out, xbf, wqkv_bf, wout_bf);
    // [1] QKV projection, scatter bf16 epilogue (V transposed)
    gemm_bt_kernel<1><<<dim3(64, 24), blk, 0, stream>>>(xbf, wqkv_bf, nullptr, qkv_ws,
                                                        8192, 3072, 1024);
    // [2] flash attention (reads qkv, writes ctx over the dead x_bf16 slot)
    flash_kernel<<<dim3(32, 64), blk, 0, stream>>>(qkv_ws, qkv_ws + QS, qkv_ws + 2 * (size_t)QS,
                                                   ctx_ws);
    // [3] output projection + bias -> f32 out
    gemm_bt_kernel<0><<<dim3(64, 8), blk, 0, stream>>>(ctx_ws, wout_bf, b_out, out,
                                                       8192, 1024, 1024);
}